// Round 4
// baseline (477.189 us; speedup 1.0000x reference)
//
#include <hip/hip_runtime.h>
#include <hip/hip_bf16.h>

#define BATCH 4
#define CH 64
#define NPIX 4096
#define NEGV -1e9f

// ws layout (floats): q [B*N*8] | k [B*N*8] | v [B*N*64]
#define WS_Q 0
#define WS_K (BATCH * NPIX * 8)                 // 131072
#define WS_V (2 * BATCH * NPIX * 8)             // 262144

#define SCP 68   // padded row stride for P tile; 68%32=4 breaks bank aliasing, 16B aligned

// ---------------- projections: q = Wq x + bq, k, v ----------------
// grid (64, 10): x = 256-pixel tile, y = output group (0=q, 1=k, 2..9 = v rows 8g)
__global__ __launch_bounds__(256) void proj_kernel(
    const float* __restrict__ x,
    const float* __restrict__ Wq, const float* __restrict__ bq,
    const float* __restrict__ Wk, const float* __restrict__ bk,
    const float* __restrict__ Wv, const float* __restrict__ bv,
    float* __restrict__ ws)
{
    __shared__ float wsh[8 * 64];
    __shared__ float bsh[8];
    const int g = blockIdx.y;
    const float* W;
    const float* bias;
    if (g == 0)      { W = Wq;                  bias = bq; }
    else if (g == 1) { W = Wk;                  bias = bk; }
    else             { W = Wv + (g - 2) * 512;  bias = bv + (g - 2) * 8; }

    const int tid = threadIdx.x;
    for (int i = tid; i < 512; i += 256) wsh[i] = W[i];
    if (tid < 8) bsh[tid] = bias[tid];
    __syncthreads();

    const int pix = blockIdx.x * 256 + tid;          // 0..16383
    const int b = pix >> 12;
    const int n = pix & (NPIX - 1);
    const float* xb = x + (size_t)b * CH * NPIX + n;

    float acc[8];
#pragma unroll
    for (int o = 0; o < 8; o++) acc[o] = bsh[o];

#pragma unroll 4
    for (int c4 = 0; c4 < 16; c4++) {
        float xv0 = xb[(size_t)(c4 * 4 + 0) * NPIX];
        float xv1 = xb[(size_t)(c4 * 4 + 1) * NPIX];
        float xv2 = xb[(size_t)(c4 * 4 + 2) * NPIX];
        float xv3 = xb[(size_t)(c4 * 4 + 3) * NPIX];
#pragma unroll
        for (int o = 0; o < 8; o++) {
            float4 w = *(const float4*)&wsh[o * 64 + c4 * 4];
            acc[o] += w.x * xv0 + w.y * xv1 + w.z * xv2 + w.w * xv3;
        }
    }

    float* dst;
    if (g == 0)      dst = ws + WS_Q + (size_t)pix * 8;
    else if (g == 1) dst = ws + WS_K + (size_t)pix * 8;
    else             dst = ws + WS_V + (size_t)pix * 64 + (g - 2) * 8;
#pragma unroll
    for (int o = 0; o < 8; o++) dst[o] = acc[o];
}

// ---------------- flash attention over 64-query tiles ----------------
// grid (64, 4): x = query tile, y = batch. 256 threads: thread t owns
// query row qr = t>>2 and channels cb = (t&3)*16 .. +16.
__global__ __launch_bounds__(256) void attn_kernel(
    const float* __restrict__ ws, const int* __restrict__ mask,
    const float* __restrict__ x, const float* __restrict__ gamma,
    float* __restrict__ out)
{
    __shared__ float qs[64 * 8];
    __shared__ float ks[64 * 8];
    __shared__ float vs[64 * 64];
    __shared__ float sc[64 * SCP];
    __shared__ int qm[64];
    __shared__ int km[64];

    const float* wq = ws + WS_Q;
    const float* wk = ws + WS_K;
    const float* wv = ws + WS_V;

    const int b = blockIdx.y;
    const int i0 = blockIdx.x * 64;
    const int tid = threadIdx.x;
    const int qr = tid >> 2;
    const int jc = tid & 3;
    const int cb = jc * 16;

    if (tid < 128)
        ((float4*)qs)[tid] = ((const float4*)(wq + (size_t)(b * NPIX + i0) * 8))[tid];
    if (tid < 64)
        qm[tid] = mask[b * NPIX + i0 + tid];

    float m = -1e30f, l = 0.f;
    float acc[16];
#pragma unroll
    for (int t = 0; t < 16; t++) acc[t] = 0.f;

    for (int j0 = 0; j0 < NPIX; j0 += 64) {
        __syncthreads();   // prior-iter P/V readers done (also publishes q staging on iter 0)
        // ---- stage K tile (64x8), key mask, V tile (64x64) ----
        if (tid < 128)
            ((float4*)ks)[tid] = ((const float4*)(wk + (size_t)(b * NPIX + j0) * 8))[tid];
        if (tid < 64)
            km[tid] = mask[b * NPIX + j0 + tid];
        {
            const float4* vsrc = (const float4*)(wv + (size_t)(b * NPIX + j0) * 64);
            float4* vdst = (float4*)vs;
#pragma unroll
            for (int u = 0; u < 4; u++) vdst[tid + 256 * u] = vsrc[tid + 256 * u];
        }
        __syncthreads();

        // ---- scores: thread computes s(qr, jc*16+idx), idx 0..15 ----
        const float4 qa = *(const float4*)(qs + qr * 8);
        const float4 qb = *(const float4*)(qs + qr * 8 + 4);
        const int qvalid = qm[qr];
        float sreg[16];
        float tmax = -3e38f;
#pragma unroll
        for (int idx = 0; idx < 16; idx++) {
            const int j = jc * 16 + idx;
            const float4 ka = *(const float4*)(ks + j * 8);
            const float4 kb = *(const float4*)(ks + j * 8 + 4);
            float s = qa.x * ka.x + qa.y * ka.y + qa.z * ka.z + qa.w * ka.w
                    + qb.x * kb.x + qb.y * kb.y + qb.z * kb.z + qb.w * kb.w;
            s = (qvalid && km[j]) ? s : NEGV;
            sreg[idx] = s;
            tmax = fmaxf(tmax, s);
        }
        // row reduction across the 4 lanes that share row qr
        tmax = fmaxf(tmax, __shfl_xor(tmax, 1));
        tmax = fmaxf(tmax, __shfl_xor(tmax, 2));
        const float m_new = fmaxf(m, tmax);
        const float alpha = __expf(m - m_new);
        float psum = 0.f;
#pragma unroll
        for (int idx = 0; idx < 16; idx += 4) {
            float4 p4;
            p4.x = __expf(sreg[idx + 0] - m_new);
            p4.y = __expf(sreg[idx + 1] - m_new);
            p4.z = __expf(sreg[idx + 2] - m_new);
            p4.w = __expf(sreg[idx + 3] - m_new);
            *(float4*)(sc + qr * SCP + jc * 16 + idx) = p4;
            psum += p4.x + p4.y + p4.z + p4.w;
        }
        psum += __shfl_xor(psum, 1);
        psum += __shfl_xor(psum, 2);
        l = l * alpha + psum;
        m = m_new;

        // cross-lane P exchange goes through LDS: barrier orders writes vs reads.
        __syncthreads();

        // ---- accumulate: acc[c] = acc[c]*alpha + sum_j p_j * v[j][c] ----
#pragma unroll
        for (int t = 0; t < 16; t++) acc[t] *= alpha;
        const float* scrow = sc + qr * SCP;
#pragma unroll 4
        for (int j4 = 0; j4 < 64; j4 += 4) {
            const float4 p4 = *(const float4*)(scrow + j4);
#pragma unroll
            for (int e = 0; e < 4; e++) {
                const float p = (&p4.x)[e];
                const float4* vv = (const float4*)(vs + (j4 + e) * 64 + cb);
                const float4 v0 = vv[0], v1 = vv[1], v2 = vv[2], v3 = vv[3];
                acc[0]  += p * v0.x; acc[1]  += p * v0.y; acc[2]  += p * v0.z; acc[3]  += p * v0.w;
                acc[4]  += p * v1.x; acc[5]  += p * v1.y; acc[6]  += p * v1.z; acc[7]  += p * v1.w;
                acc[8]  += p * v2.x; acc[9]  += p * v2.y; acc[10] += p * v2.z; acc[11] += p * v2.w;
                acc[12] += p * v3.x; acc[13] += p * v3.y; acc[14] += p * v3.z; acc[15] += p * v3.w;
            }
        }
    }

    // ---- epilogue: out = gamma * (acc/l) + x (fp32 out!), transposed via LDS ----
    const float inv = 1.f / l;       // l >= 1 always
    const float gm = gamma[0];
    __syncthreads();                 // all waves done with sc/vs
#pragma unroll
    for (int t = 0; t < 16; t++) sc[(cb + t) * SCP + qr] = acc[t] * inv;
    __syncthreads();
    const int c = tid >> 2;
    const int n0 = (tid & 3) * 16;
    const size_t base = (size_t)(b * CH + c) * NPIX + i0 + n0;
#pragma unroll
    for (int t = 0; t < 16; t++) {
        const float o = sc[c * SCP + n0 + t];
        out[base + t] = gm * o + x[base + t];
    }
}

extern "C" void kernel_launch(void* const* d_in, const int* in_sizes, int n_in,
                              void* d_out, int out_size, void* d_ws, size_t ws_size,
                              hipStream_t stream) {
    const float* x     = (const float*)d_in[0];
    const int*   mask  = (const int*)d_in[1];
    const float* Wq    = (const float*)d_in[2];
    const float* bq    = (const float*)d_in[3];
    const float* Wk    = (const float*)d_in[4];
    const float* bk    = (const float*)d_in[5];
    const float* Wv    = (const float*)d_in[6];
    const float* bv    = (const float*)d_in[7];
    const float* gamma = (const float*)d_in[8];
    float* out = (float*)d_out;                // fp32: reference output dtype is float32
    float* ws  = (float*)d_ws;                 // needs 1,310,720 floats = 5.25 MB

    proj_kernel<<<dim3(64, 10), 256, 0, stream>>>(x, Wq, bq, Wk, bk, Wv, bv, ws);
    attn_kernel<<<dim3(64, 4), 256, 0, stream>>>(ws, mask, x, gamma, out);
}

// Round 5
// 152.671 us; speedup vs baseline: 3.1256x; 3.1256x over previous
//
#include <hip/hip_runtime.h>

typedef unsigned int uint;
typedef unsigned short ushort;
typedef __attribute__((ext_vector_type(8))) short short8;   // 8 bf16 MFMA A/B frag
typedef __attribute__((ext_vector_type(4))) float f32x4;    // MFMA C/D frag
typedef __attribute__((ext_vector_type(4))) uint  uint4v;   // 16B mover

#define BATCH 4
#define CH 64
#define NPIX 4096
#define NEGV -1e9f

// ws layout (ushort elements): q[b][n][8] | k[b][n][8] | vt[b][c][n]   all bf16
#define WSQ 0
#define WSK (BATCH * NPIX * 8)            // 131072
#define WSV (2 * BATCH * NPIX * 8)        // 262144  (vt: 4*64*4096 = 1048576 u16)

// f32 -> bf16 bits, round-to-nearest-even
__device__ __forceinline__ ushort f2bf(float f) {
    union { float f; uint u; } a; a.f = f;
    uint u = a.u;
    return (ushort)((u + 0x7FFFu + ((u >> 16) & 1u)) >> 16);
}

// ---------------- projections -> bf16 q,k and bf16 V^T ----------------
// grid (64, 10): x = 256-pixel tile, y = output group (0=q, 1=k, 2..9 = v rows 8g)
__global__ __launch_bounds__(256) void proj_kernel(
    const float* __restrict__ x,
    const float* __restrict__ Wq, const float* __restrict__ bq,
    const float* __restrict__ Wk, const float* __restrict__ bk,
    const float* __restrict__ Wv, const float* __restrict__ bv,
    ushort* __restrict__ ws)
{
    __shared__ float wsh[8 * 64];
    __shared__ float bsh[8];
    const int g = blockIdx.y;
    const float* W;
    const float* bias;
    if (g == 0)      { W = Wq;                  bias = bq; }
    else if (g == 1) { W = Wk;                  bias = bk; }
    else             { W = Wv + (g - 2) * 512;  bias = bv + (g - 2) * 8; }

    const int tid = threadIdx.x;
    for (int i = tid; i < 512; i += 256) wsh[i] = W[i];
    if (tid < 8) bsh[tid] = bias[tid];
    __syncthreads();

    const int pix = blockIdx.x * 256 + tid;          // 0..16383
    const int b = pix >> 12;
    const int n = pix & (NPIX - 1);
    const float* xb = x + (size_t)b * CH * NPIX + n;

    float acc[8];
#pragma unroll
    for (int o = 0; o < 8; o++) acc[o] = bsh[o];

#pragma unroll 4
    for (int c4 = 0; c4 < 16; c4++) {
        float xv0 = xb[(size_t)(c4 * 4 + 0) * NPIX];
        float xv1 = xb[(size_t)(c4 * 4 + 1) * NPIX];
        float xv2 = xb[(size_t)(c4 * 4 + 2) * NPIX];
        float xv3 = xb[(size_t)(c4 * 4 + 3) * NPIX];
#pragma unroll
        for (int o = 0; o < 8; o++) {
            float4 w = *(const float4*)&wsh[o * 64 + c4 * 4];
            acc[o] += w.x * xv0 + w.y * xv1 + w.z * xv2 + w.w * xv3;
        }
    }

    if (g <= 1) {
        uint4v pk;
        pk.x = (uint)f2bf(acc[0]) | ((uint)f2bf(acc[1]) << 16);
        pk.y = (uint)f2bf(acc[2]) | ((uint)f2bf(acc[3]) << 16);
        pk.z = (uint)f2bf(acc[4]) | ((uint)f2bf(acc[5]) << 16);
        pk.w = (uint)f2bf(acc[6]) | ((uint)f2bf(acc[7]) << 16);
        uint4v* dst = (uint4v*)(ws + (g == 0 ? WSQ : WSK));
        dst[pix] = pk;                                   // 16B per pixel, coalesced
    } else {
        // V^T: vt[b][c][n], coalesced in n across lanes
        ushort* vt = ws + WSV;
        const int c0 = (g - 2) * 8;
#pragma unroll
        for (int o = 0; o < 8; o++)
            vt[(((size_t)b * CH + c0 + o) << 12) + n] = f2bf(acc[o]);
    }
}

// ---------------- MFMA flash attention ----------------
// grid (128, 4): 32-query tile per block, 256 thr = 4 waves.
// wave wid: rowgrp = wid>>1 (16 rows), parity = wid&1 (even/odd 64-key tiles).
__global__ __launch_bounds__(256, 2) void attn_kernel(
    const ushort* __restrict__ ws, const int* __restrict__ mask,
    const float* __restrict__ x, const float* __restrict__ gamma,
    float* __restrict__ out)
{
    __shared__ ushort Klds[2][64][8];      // [buf][key][d]
    __shared__ ushort Vlds[2][64][72];     // [buf][channel][j], pad 64->72
    __shared__ ushort Plds[4][16][72];     // per-wave P [m][j], pad
    __shared__ ushort Qlds[32][8];
    __shared__ int    kmld[128];
    __shared__ int    qmld[32];
    __shared__ float  Mbuf[32], Lbuf[32];  // [rg*16+row]
    __shared__ float  Xbuf[2][16][68];     // partner acc exchange
    __shared__ float  Fbuf[32][65];        // merged output for epilogue

    const int tid  = threadIdx.x;
    const int wid  = tid >> 6;
    const int lane = tid & 63;
    const int quad = lane >> 4;
    const int col  = lane & 15;
    const int rg   = wid >> 1;
    const int par  = wid & 1;
    const int b    = blockIdx.y;
    const int i0   = blockIdx.x * 32;

    const ushort* qb = ws + WSQ + (size_t)b * NPIX * 8;
    const ushort* kb = ws + WSK + (size_t)b * NPIX * 8;
    const ushort* vb = ws + WSV + ((size_t)b * CH << 12);

    if (tid < 32) {
        ((uint4v*)Qlds)[tid] = ((const uint4v*)qb)[i0 + tid];
        qmld[tid] = mask[b * NPIX + i0 + tid];
    }
    __syncthreads();

    const short8 z8 = {0, 0, 0, 0, 0, 0, 0, 0};
    const f32x4 zf = {0.f, 0.f, 0.f, 0.f};

    // Q A-frag: A[m=col][k=quad*8+j]; only k<8 real -> quad 0 only
    short8 qfrag;
    {
        short8 v = *(const short8*)&Qlds[rg * 16 + col][0];
        qfrag = (quad == 0) ? v : z8;
    }
    int qvi[4];
#pragma unroll
    for (int r = 0; r < 4; r++) qvi[r] = qmld[rg * 16 + quad * 4 + r];

    float mrow[4], lrow[4];
    f32x4 acc[4];
#pragma unroll
    for (int r = 0; r < 4; r++) { mrow[r] = -1e30f; lrow[r] = 0.f; }
#pragma unroll
    for (int nt = 0; nt < 4; nt++) acc[nt] = zf;

    for (int t = 0; t < 32; t++) {
        __syncthreads();   // prior consumption of both buffers done
        // ---- stage K pair + key-mask pair + V^T pair ----
        if (tid < 128) {
            const int pix = t * 128 + tid;
            *(uint4v*)&Klds[tid >> 6][tid & 63][0] = *(const uint4v*)&kb[(size_t)pix * 8];
        } else {
            const int idx = tid - 128;
            kmld[idx] = mask[b * NPIX + t * 128 + idx];
        }
        {
            const int c = tid >> 2, seg = tid & 3;
            const ushort* src = vb + ((size_t)c << 12) + t * 128 + seg * 32;
            ushort* dst = &Vlds[seg >> 1][c][(seg & 1) * 32];
#pragma unroll
            for (int gi = 0; gi < 4; gi++) ((uint4v*)dst)[gi] = ((const uint4v*)src)[gi];
        }
        __syncthreads();

        // ---- QK^T: 4 subtiles of 16 keys ----
        const int jb = par * 64;
        f32x4 s[4];
#pragma unroll
        for (int st = 0; st < 4; st++) {
            short8 kf = *(const short8*)&Klds[par][st * 16 + col][0];
            kf = (quad == 0) ? kf : z8;
            s[st] = __builtin_amdgcn_mfma_f32_16x16x32_bf16(qfrag, kf, zf, 0, 0, 0);
        }

        // ---- mask + online softmax (rows = quad*4+r, 16 lanes/row) ----
        int kvi[4];
#pragma unroll
        for (int st = 0; st < 4; st++) kvi[st] = kmld[jb + st * 16 + col];
        float p[4][4];
        float tmax[4] = {-3e38f, -3e38f, -3e38f, -3e38f};
#pragma unroll
        for (int st = 0; st < 4; st++)
#pragma unroll
            for (int r = 0; r < 4; r++) {
                float sv = (qvi[r] && kvi[st]) ? s[st][r] : NEGV;
                p[st][r] = sv;
                tmax[r] = fmaxf(tmax[r], sv);
            }
#pragma unroll
        for (int r = 0; r < 4; r++) {
            tmax[r] = fmaxf(tmax[r], __shfl_xor(tmax[r], 1));
            tmax[r] = fmaxf(tmax[r], __shfl_xor(tmax[r], 2));
            tmax[r] = fmaxf(tmax[r], __shfl_xor(tmax[r], 4));
            tmax[r] = fmaxf(tmax[r], __shfl_xor(tmax[r], 8));
        }
        float alpha[4];
#pragma unroll
        for (int r = 0; r < 4; r++) {
            const float mn = fmaxf(mrow[r], tmax[r]);
            alpha[r] = __expf(mrow[r] - mn);
            mrow[r] = mn;
        }
        float psum[4] = {0.f, 0.f, 0.f, 0.f};
#pragma unroll
        for (int st = 0; st < 4; st++)
#pragma unroll
            for (int r = 0; r < 4; r++) {
                const float e = __expf(p[st][r] - mrow[r]);
                p[st][r] = e;
                psum[r] += e;
            }
#pragma unroll
        for (int r = 0; r < 4; r++) {
            psum[r] += __shfl_xor(psum[r], 1);
            psum[r] += __shfl_xor(psum[r], 2);
            psum[r] += __shfl_xor(psum[r], 4);
            psum[r] += __shfl_xor(psum[r], 8);
            lrow[r] = lrow[r] * alpha[r] + psum[r];
        }
#pragma unroll
        for (int nt = 0; nt < 4; nt++)
#pragma unroll
            for (int r = 0; r < 4; r++) acc[nt][r] *= alpha[r];

        // ---- P: C-layout -> LDS [m][j] (wave-private) -> A-frags ----
        ushort* pw = &Plds[wid][0][0];
#pragma unroll
        for (int st = 0; st < 4; st++)
#pragma unroll
            for (int r = 0; r < 4; r++)
                pw[(quad * 4 + r) * 72 + st * 16 + col] = f2bf(p[st][r]);
        __asm__ volatile("s_waitcnt lgkmcnt(0)" ::: "memory");
        const short8 pf0 = *(const short8*)&Plds[wid][col][quad * 8];
        const short8 pf1 = *(const short8*)&Plds[wid][col][32 + quad * 8];

        // ---- PV: O[m][c] += P[m][j] V[j][c], B-frags from V^T ----
#pragma unroll
        for (int nt = 0; nt < 4; nt++) {
            const short8 v0 = *(const short8*)&Vlds[par][nt * 16 + col][quad * 8];
            acc[nt] = __builtin_amdgcn_mfma_f32_16x16x32_bf16(pf0, v0, acc[nt], 0, 0, 0);
            const short8 v1 = *(const short8*)&Vlds[par][nt * 16 + col][32 + quad * 8];
            acc[nt] = __builtin_amdgcn_mfma_f32_16x16x32_bf16(pf1, v1, acc[nt], 0, 0, 0);
        }
    }

    // ---- merge wave pairs (same rows, opposite key parity) ----
    if (par == 1) {
#pragma unroll
        for (int r = 0; r < 4; r++)
            if (col == 0) {
                Mbuf[rg * 16 + quad * 4 + r] = mrow[r];
                Lbuf[rg * 16 + quad * 4 + r] = lrow[r];
            }
#pragma unroll
        for (int nt = 0; nt < 4; nt++)
#pragma unroll
            for (int r = 0; r < 4; r++)
                Xbuf[rg][quad * 4 + r][nt * 16 + col] = acc[nt][r];
    }
    __syncthreads();
    if (par == 0) {
        float a0[4], a1[4], inv[4];
#pragma unroll
        for (int r = 0; r < 4; r++) {
            const float m1 = Mbuf[rg * 16 + quad * 4 + r];
            const float l1 = Lbuf[rg * 16 + quad * 4 + r];
            const float M = fmaxf(mrow[r], m1);
            a0[r] = __expf(mrow[r] - M);
            a1[r] = __expf(m1 - M);
            inv[r] = 1.f / (a0[r] * lrow[r] + a1[r] * l1);
        }
#pragma unroll
        for (int nt = 0; nt < 4; nt++)
#pragma unroll
            for (int r = 0; r < 4; r++) {
                const float o1 = Xbuf[rg][quad * 4 + r][nt * 16 + col];
                Fbuf[rg * 16 + quad * 4 + r][nt * 16 + col] =
                    (a0[r] * acc[nt][r] + a1[r] * o1) * inv[r];
            }
    }
    __syncthreads();

    // ---- epilogue: out = gamma * O + x, coalesced fp32 ----
    const float gm = gamma[0];
    const int c = tid >> 2, seg = tid & 3;
    const size_t base = (((size_t)(b * CH + c)) << 12) + i0 + seg * 8;
    f32x4 x0 = ((const f32x4*)&x[base])[0];
    f32x4 x1 = ((const f32x4*)&x[base])[1];
    f32x4 o0, o1;
#pragma unroll
    for (int u = 0; u < 4; u++) {
        o0[u] = gm * Fbuf[seg * 8 + u][c] + x0[u];
        o1[u] = gm * Fbuf[seg * 8 + 4 + u][c] + x1[u];
    }
    ((f32x4*)&out[base])[0] = o0;
    ((f32x4*)&out[base])[1] = o1;
}

extern "C" void kernel_launch(void* const* d_in, const int* in_sizes, int n_in,
                              void* d_out, int out_size, void* d_ws, size_t ws_size,
                              hipStream_t stream) {
    const float* x     = (const float*)d_in[0];
    const int*   mask  = (const int*)d_in[1];
    const float* Wq    = (const float*)d_in[2];
    const float* bq    = (const float*)d_in[3];
    const float* Wk    = (const float*)d_in[4];
    const float* bk    = (const float*)d_in[5];
    const float* Wv    = (const float*)d_in[6];
    const float* bv    = (const float*)d_in[7];
    const float* gamma = (const float*)d_in[8];
    float* out  = (float*)d_out;
    ushort* ws  = (ushort*)d_ws;    // 1,310,720 u16 = 2.62 MB

    proj_kernel<<<dim3(64, 10), 256, 0, stream>>>(x, Wq, bq, Wk, bk, Wv, bv, ws);
    attn_kernel<<<dim3(128, 4), 256, 0, stream>>>(ws, mask, x, gamma, out);
}

// Round 6
// 143.973 us; speedup vs baseline: 3.3144x; 1.0604x over previous
//
#include <hip/hip_runtime.h>

typedef unsigned int uint;
typedef unsigned short ushort;
typedef __attribute__((ext_vector_type(8))) short short8;   // 8 bf16 MFMA A/B frag
typedef __attribute__((ext_vector_type(4))) float f32x4;    // MFMA C/D frag
typedef __attribute__((ext_vector_type(4))) uint  uint4v;   // 16B mover

#define BATCH 4
#define CH 64
#define NPIX 4096
#define NEGV -1e9f

// ws layout (ushort elements): q[b][n][8] | k[b][n][8] | vt[b][c][n]   all bf16
#define WSQ 0
#define WSK (BATCH * NPIX * 8)            // 131072
#define WSV (2 * BATCH * NPIX * 8)        // 262144  (vt: 4*64*4096 = 1048576 u16)

// f32 -> bf16 bits, round-to-nearest-even
__device__ __forceinline__ ushort f2bf(float f) {
    union { float f; uint u; } a; a.f = f;
    uint u = a.u;
    return (ushort)((u + 0x7FFFu + ((u >> 16) & 1u)) >> 16);
}

// ---------------- projections -> bf16 q,k and bf16 V^T ----------------
// grid (64, 10): x = 256-pixel tile, y = output group (0=q, 1=k, 2..9 = v rows 8g)
__global__ __launch_bounds__(256) void proj_kernel(
    const float* __restrict__ x,
    const float* __restrict__ Wq, const float* __restrict__ bq,
    const float* __restrict__ Wk, const float* __restrict__ bk,
    const float* __restrict__ Wv, const float* __restrict__ bv,
    ushort* __restrict__ ws)
{
    __shared__ float wsh[8 * 64];
    __shared__ float bsh[8];
    const int g = blockIdx.y;
    const float* W;
    const float* bias;
    if (g == 0)      { W = Wq;                  bias = bq; }
    else if (g == 1) { W = Wk;                  bias = bk; }
    else             { W = Wv + (g - 2) * 512;  bias = bv + (g - 2) * 8; }

    const int tid = threadIdx.x;
    for (int i = tid; i < 512; i += 256) wsh[i] = W[i];
    if (tid < 8) bsh[tid] = bias[tid];
    __syncthreads();

    const int pix = blockIdx.x * 256 + tid;          // 0..16383
    const int b = pix >> 12;
    const int n = pix & (NPIX - 1);
    const float* xb = x + (size_t)b * CH * NPIX + n;

    float acc[8];
#pragma unroll
    for (int o = 0; o < 8; o++) acc[o] = bsh[o];

    // full unroll: all 64 loads in flight (latency-bound at 2.5 waves/SIMD)
#pragma unroll
    for (int c4 = 0; c4 < 16; c4++) {
        float xv0 = xb[(size_t)(c4 * 4 + 0) * NPIX];
        float xv1 = xb[(size_t)(c4 * 4 + 1) * NPIX];
        float xv2 = xb[(size_t)(c4 * 4 + 2) * NPIX];
        float xv3 = xb[(size_t)(c4 * 4 + 3) * NPIX];
#pragma unroll
        for (int o = 0; o < 8; o++) {
            float4 w = *(const float4*)&wsh[o * 64 + c4 * 4];
            acc[o] += w.x * xv0 + w.y * xv1 + w.z * xv2 + w.w * xv3;
        }
    }

    if (g <= 1) {
        uint4v pk;
        pk.x = (uint)f2bf(acc[0]) | ((uint)f2bf(acc[1]) << 16);
        pk.y = (uint)f2bf(acc[2]) | ((uint)f2bf(acc[3]) << 16);
        pk.z = (uint)f2bf(acc[4]) | ((uint)f2bf(acc[5]) << 16);
        pk.w = (uint)f2bf(acc[6]) | ((uint)f2bf(acc[7]) << 16);
        uint4v* dst = (uint4v*)(ws + (g == 0 ? WSQ : WSK));
        dst[pix] = pk;                                   // 16B per pixel, coalesced
    } else {
        // V^T: vt[b][c][n], coalesced in n across lanes
        ushort* vt = ws + WSV;
        const int c0 = (g - 2) * 8;
#pragma unroll
        for (int o = 0; o < 8; o++)
            vt[(((size_t)b * CH + c0 + o) << 12) + n] = f2bf(acc[o]);
    }
}

// ---------------- MFMA flash attention, software-pipelined K-loop ----------------
// grid (128, 4): 32-query tile per block, 256 thr = 4 waves.
// wave wid: rowgrp = wid>>1 (16 rows), parity = wid&1 (even/odd 64-key tiles).
__global__ __launch_bounds__(256, 2) void attn_kernel(
    const ushort* __restrict__ ws, const int* __restrict__ mask,
    const float* __restrict__ x, const float* __restrict__ gamma,
    float* __restrict__ out)
{
    __shared__ ushort Klds[2][64][8];      // [buf][key][d]
    __shared__ ushort Vlds[2][64][72];     // [buf][channel][j], pad 64->72
    __shared__ ushort Plds[4][16][72];     // per-wave P [m][j], pad
    __shared__ ushort Qlds[32][8];
    __shared__ int    kmld[128];
    __shared__ int    qmld[32];
    __shared__ float  Mbuf[32], Lbuf[32];  // [rg*16+row]
    __shared__ float  Xbuf[2][16][68];     // partner acc exchange
    __shared__ float  Fbuf[32][65];        // merged output for epilogue

    const int tid  = threadIdx.x;
    const int wid  = tid >> 6;
    const int lane = tid & 63;
    const int quad = lane >> 4;
    const int col  = lane & 15;
    const int rg   = wid >> 1;
    const int par  = wid & 1;
    const int b    = blockIdx.y;
    const int i0   = blockIdx.x * 32;

    const ushort* qb = ws + WSQ + (size_t)b * NPIX * 8;
    const ushort* kb = ws + WSK + (size_t)b * NPIX * 8;
    const ushort* vb = ws + WSV + ((size_t)b * CH << 12);

    if (tid < 32) {
        ((uint4v*)Qlds)[tid] = ((const uint4v*)qb)[i0 + tid];
        qmld[tid] = mask[b * NPIX + i0 + tid];
    }
    __syncthreads();

    const short8 z8 = {0, 0, 0, 0, 0, 0, 0, 0};
    const f32x4 zf = {0.f, 0.f, 0.f, 0.f};

    // Q A-frag: A[m=col][k=quad*8+j]; only k<8 real -> quad 0 only
    short8 qfrag;
    {
        short8 v = *(const short8*)&Qlds[rg * 16 + col][0];
        qfrag = (quad == 0) ? v : z8;
    }
    int qvi[4];
#pragma unroll
    for (int r = 0; r < 4; r++) qvi[r] = qmld[rg * 16 + quad * 4 + r];

    float mrow[4], lrow[4];
    f32x4 acc[4];
#pragma unroll
    for (int r = 0; r < 4; r++) { mrow[r] = -1e30f; lrow[r] = 0.f; }
#pragma unroll
    for (int nt = 0; nt < 4; nt++) acc[nt] = zf;

    // ---- software pipeline: prefetch tile t+1 into regs during compute of t ----
    const int vc = tid >> 2, vseg = tid & 3;
    const ushort* vsrc_base = vb + ((size_t)vc << 12) + vseg * 32;
    uint4v kreg = {0,0,0,0};
    int    mreg = 0;
    uint4v vreg0, vreg1, vreg2, vreg3;

#define ISSUE_LOADS(tt) do {                                                     \
        if (tid < 128) kreg = *(const uint4v*)&kb[(size_t)((tt) * 128 + tid) * 8]; \
        else           mreg = mask[b * NPIX + (tt) * 128 + (tid - 128)];          \
        const uint4v* vs4 = (const uint4v*)(vsrc_base + (tt) * 128);              \
        vreg0 = vs4[0]; vreg1 = vs4[1]; vreg2 = vs4[2]; vreg3 = vs4[3];           \
    } while (0)

    ISSUE_LOADS(0);

    for (int t = 0; t < 32; t++) {
        __syncthreads();   // prev-iter LDS consumers done (and Q staging on t=0)
        // ---- drain prefetch regs into LDS ----
        if (tid < 128) *(uint4v*)&Klds[tid >> 6][tid & 63][0] = kreg;
        else           kmld[tid - 128] = mreg;
        {
            ushort* dst = &Vlds[vseg >> 1][vc][(vseg & 1) * 32];
            ((uint4v*)dst)[0] = vreg0; ((uint4v*)dst)[1] = vreg1;
            ((uint4v*)dst)[2] = vreg2; ((uint4v*)dst)[3] = vreg3;
        }
        __syncthreads();
        if (t < 31) ISSUE_LOADS(t + 1);   // loads fly under compute below

        // ---- QK^T: 4 subtiles of 16 keys ----
        const int jb = par * 64;
        f32x4 s[4];
#pragma unroll
        for (int st = 0; st < 4; st++) {
            short8 kf = *(const short8*)&Klds[par][st * 16 + col][0];
            kf = (quad == 0) ? kf : z8;
            s[st] = __builtin_amdgcn_mfma_f32_16x16x32_bf16(qfrag, kf, zf, 0, 0, 0);
        }

        // ---- mask + online softmax (rows = quad*4+r, 16 lanes/row) ----
        int kvi[4];
#pragma unroll
        for (int st = 0; st < 4; st++) kvi[st] = kmld[jb + st * 16 + col];
        float p[4][4];
        float tmax[4] = {-3e38f, -3e38f, -3e38f, -3e38f};
#pragma unroll
        for (int st = 0; st < 4; st++)
#pragma unroll
            for (int r = 0; r < 4; r++) {
                float sv = (qvi[r] && kvi[st]) ? s[st][r] : NEGV;
                p[st][r] = sv;
                tmax[r] = fmaxf(tmax[r], sv);
            }
#pragma unroll
        for (int r = 0; r < 4; r++) {
            tmax[r] = fmaxf(tmax[r], __shfl_xor(tmax[r], 1));
            tmax[r] = fmaxf(tmax[r], __shfl_xor(tmax[r], 2));
            tmax[r] = fmaxf(tmax[r], __shfl_xor(tmax[r], 4));
            tmax[r] = fmaxf(tmax[r], __shfl_xor(tmax[r], 8));
        }
        float alpha[4];
#pragma unroll
        for (int r = 0; r < 4; r++) {
            const float mn = fmaxf(mrow[r], tmax[r]);
            alpha[r] = __expf(mrow[r] - mn);
            mrow[r] = mn;
        }
        float psum[4] = {0.f, 0.f, 0.f, 0.f};
#pragma unroll
        for (int st = 0; st < 4; st++)
#pragma unroll
            for (int r = 0; r < 4; r++) {
                const float e = __expf(p[st][r] - mrow[r]);
                p[st][r] = e;
                psum[r] += e;
            }
#pragma unroll
        for (int r = 0; r < 4; r++) {
            psum[r] += __shfl_xor(psum[r], 1);
            psum[r] += __shfl_xor(psum[r], 2);
            psum[r] += __shfl_xor(psum[r], 4);
            psum[r] += __shfl_xor(psum[r], 8);
            lrow[r] = lrow[r] * alpha[r] + psum[r];
        }
#pragma unroll
        for (int nt = 0; nt < 4; nt++)
#pragma unroll
            for (int r = 0; r < 4; r++) acc[nt][r] *= alpha[r];

        // ---- P: C-layout -> LDS [m][j] (wave-private) -> A-frags ----
        ushort* pw = &Plds[wid][0][0];
#pragma unroll
        for (int st = 0; st < 4; st++)
#pragma unroll
            for (int r = 0; r < 4; r++)
                pw[(quad * 4 + r) * 72 + st * 16 + col] = f2bf(p[st][r]);
        __asm__ volatile("s_waitcnt lgkmcnt(0)" ::: "memory");
        const short8 pf0 = *(const short8*)&Plds[wid][col][quad * 8];
        const short8 pf1 = *(const short8*)&Plds[wid][col][32 + quad * 8];

        // ---- PV: O[m][c] += P[m][j] V[j][c], B-frags from V^T ----
#pragma unroll
        for (int nt = 0; nt < 4; nt++) {
            const short8 v0 = *(const short8*)&Vlds[par][nt * 16 + col][quad * 8];
            acc[nt] = __builtin_amdgcn_mfma_f32_16x16x32_bf16(pf0, v0, acc[nt], 0, 0, 0);
            const short8 v1 = *(const short8*)&Vlds[par][nt * 16 + col][32 + quad * 8];
            acc[nt] = __builtin_amdgcn_mfma_f32_16x16x32_bf16(pf1, v1, acc[nt], 0, 0, 0);
        }
    }
#undef ISSUE_LOADS

    // ---- merge wave pairs (same rows, opposite key parity) ----
    if (par == 1) {
#pragma unroll
        for (int r = 0; r < 4; r++)
            if (col == 0) {
                Mbuf[rg * 16 + quad * 4 + r] = mrow[r];
                Lbuf[rg * 16 + quad * 4 + r] = lrow[r];
            }
#pragma unroll
        for (int nt = 0; nt < 4; nt++)
#pragma unroll
            for (int r = 0; r < 4; r++)
                Xbuf[rg][quad * 4 + r][nt * 16 + col] = acc[nt][r];
    }
    __syncthreads();
    if (par == 0) {
        float a0[4], a1[4], inv[4];
#pragma unroll
        for (int r = 0; r < 4; r++) {
            const float m1 = Mbuf[rg * 16 + quad * 4 + r];
            const float l1 = Lbuf[rg * 16 + quad * 4 + r];
            const float M = fmaxf(mrow[r], m1);
            a0[r] = __expf(mrow[r] - M);
            a1[r] = __expf(m1 - M);
            inv[r] = 1.f / (a0[r] * lrow[r] + a1[r] * l1);
        }
#pragma unroll
        for (int nt = 0; nt < 4; nt++)
#pragma unroll
            for (int r = 0; r < 4; r++) {
                const float o1 = Xbuf[rg][quad * 4 + r][nt * 16 + col];
                Fbuf[rg * 16 + quad * 4 + r][nt * 16 + col] =
                    (a0[r] * acc[nt][r] + a1[r] * o1) * inv[r];
            }
    }
    __syncthreads();

    // ---- epilogue: out = gamma * O + x, coalesced fp32 ----
    const float gm = gamma[0];
    const int c = tid >> 2, seg = tid & 3;
    const size_t base = (((size_t)(b * CH + c)) << 12) + i0 + seg * 8;
    f32x4 x0 = ((const f32x4*)&x[base])[0];
    f32x4 x1 = ((const f32x4*)&x[base])[1];
    f32x4 o0, o1;
#pragma unroll
    for (int u = 0; u < 4; u++) {
        o0[u] = gm * Fbuf[seg * 8 + u][c] + x0[u];
        o1[u] = gm * Fbuf[seg * 8 + 4 + u][c] + x1[u];
    }
    ((f32x4*)&out[base])[0] = o0;
    ((f32x4*)&out[base])[1] = o1;
}

extern "C" void kernel_launch(void* const* d_in, const int* in_sizes, int n_in,
                              void* d_out, int out_size, void* d_ws, size_t ws_size,
                              hipStream_t stream) {
    const float* x     = (const float*)d_in[0];
    const int*   mask  = (const int*)d_in[1];
    const float* Wq    = (const float*)d_in[2];
    const float* bq    = (const float*)d_in[3];
    const float* Wk    = (const float*)d_in[4];
    const float* bk    = (const float*)d_in[5];
    const float* Wv    = (const float*)d_in[6];
    const float* bv    = (const float*)d_in[7];
    const float* gamma = (const float*)d_in[8];
    float* out  = (float*)d_out;
    ushort* ws  = (ushort*)d_ws;    // 1,310,720 u16 = 2.62 MB

    proj_kernel<<<dim3(64, 10), 256, 0, stream>>>(x, Wq, bq, Wk, bk, Wv, bv, ws);
    attn_kernel<<<dim3(128, 4), 256, 0, stream>>>(ws, mask, x, gamma, out);
}

// Round 7
// 101.823 us; speedup vs baseline: 4.6865x; 1.4140x over previous
//
#include <hip/hip_runtime.h>

typedef unsigned int uint;
typedef unsigned short ushort;
typedef __attribute__((ext_vector_type(8))) short short8;    // 8 bf16 MFMA A/B frag
typedef __attribute__((ext_vector_type(4))) float f32x4;
typedef __attribute__((ext_vector_type(16))) float f32x16;   // 32x32 MFMA C/D
typedef __attribute__((ext_vector_type(4))) uint uint4v;

#define BATCH 4
#define CH 64
#define NPIX 4096
#define LOG2E 1.44269504f

// ws layout (ushort elems), all bf16 in MFMA-frag-major order:
// qf[b][qt:128][h:2][m':32][jj:8]                       (d=16: 8 real + slot(qm?1:0) + zeros)
// kf[b][jt:128][h:2][j':32][jj:8]                       (d=16: 8 real + slot(km?0:-1e30) + zeros)
// vtf[b][jt:128][ct:2][h:2][hp:2][c':32][jj:8]
#define WSQ 0
#define WSK (BATCH * 128 * 512)          // 262144
#define WSV (2 * BATCH * 128 * 512)      // 524288 (vtf: 1048576 u16)

__device__ __forceinline__ ushort f2bf(float f) {            // RNE f32->bf16
    union { float f; uint u; } a; a.f = f;
    const uint u = a.u;
    return (ushort)((u + 0x7FFFu + ((u >> 16) & 1u)) >> 16);
}
__device__ __forceinline__ uint pkbf(float a, float b) {
    return (uint)f2bf(a) | ((uint)f2bf(b) << 16);
}

// ---------------- projections -> frag-major bf16 q,k,v ----------------
// grid (64, 10): x = 256-pixel tile, y = group (0=q, 1=k, 2..9 = v rows 8g)
__global__ __launch_bounds__(256) void proj_kernel(
    const float* __restrict__ x, const int* __restrict__ mask,
    const float* __restrict__ Wq, const float* __restrict__ bq,
    const float* __restrict__ Wk, const float* __restrict__ bk,
    const float* __restrict__ Wv, const float* __restrict__ bv,
    ushort* __restrict__ ws)
{
    __shared__ float wsh[8 * 64];
    __shared__ float bsh[8];
    const int g = blockIdx.y;
    const float* W;
    const float* bias;
    if (g == 0)      { W = Wq;                  bias = bq; }
    else if (g == 1) { W = Wk;                  bias = bk; }
    else             { W = Wv + (g - 2) * 512;  bias = bv + (g - 2) * 8; }

    const int tid = threadIdx.x;
    for (int i = tid; i < 512; i += 256) wsh[i] = W[i];
    if (tid < 8) bsh[tid] = bias[tid];
    __syncthreads();

    const int pix = blockIdx.x * 256 + tid;          // 0..16383
    const int b = pix >> 12;
    const int n = pix & (NPIX - 1);
    const float* xb = x + (size_t)b * CH * NPIX + n;

    float acc[8];
#pragma unroll
    for (int o = 0; o < 8; o++) acc[o] = bsh[o];

#pragma unroll
    for (int c4 = 0; c4 < 16; c4++) {
        float xv0 = xb[(size_t)(c4 * 4 + 0) * NPIX];
        float xv1 = xb[(size_t)(c4 * 4 + 1) * NPIX];
        float xv2 = xb[(size_t)(c4 * 4 + 2) * NPIX];
        float xv3 = xb[(size_t)(c4 * 4 + 3) * NPIX];
#pragma unroll
        for (int o = 0; o < 8; o++) {
            float4 w = *(const float4*)&wsh[o * 64 + c4 * 4];
            acc[o] += w.x * xv0 + w.y * xv1 + w.z * xv2 + w.w * xv3;
        }
    }

    const int jt = n >> 5, jl = n & 31;
    if (g == 0) {
        // q: fold log2(e); zero rows of invalid queries; d=8 slot = qm?1:0
        const int qm = mask[pix];
        const float s = qm ? LOG2E : 0.f;
        uint4v lo, hi;
        lo.x = pkbf(acc[0] * s, acc[1] * s);
        lo.y = pkbf(acc[2] * s, acc[3] * s);
        lo.z = pkbf(acc[4] * s, acc[5] * s);
        lo.w = pkbf(acc[6] * s, acc[7] * s);
        hi.x = qm ? 0x3F80u : 0u;   // bf16(1.0) in slot jj=0
        hi.y = 0u; hi.z = 0u; hi.w = 0u;
        ushort* qf = ws + WSQ + (size_t)b * 65536 + (size_t)jt * 512;
        *(uint4v*)(qf + jl * 8)       = lo;   // h=0: real d 0..7
        *(uint4v*)(qf + 256 + jl * 8) = hi;   // h=1: d 8..15
    } else if (g == 1) {
        // k: d=8 slot = km ? 0 : -1e30  (masked keys annihilate via exp2)
        const int km = mask[pix];
        uint4v lo, hi;
        lo.x = pkbf(acc[0], acc[1]);
        lo.y = pkbf(acc[2], acc[3]);
        lo.z = pkbf(acc[4], acc[5]);
        lo.w = pkbf(acc[6], acc[7]);
        hi.x = (uint)f2bf(km ? 0.f : -1e30f);
        hi.y = 0u; hi.z = 0u; hi.w = 0u;
        ushort* kf = ws + WSK + (size_t)b * 65536 + (size_t)jt * 512;
        *(uint4v*)(kf + jl * 8)       = lo;
        *(uint4v*)(kf + 256 + jl * 8) = hi;
    } else {
        // v: frag-major vtf[b][jt][ct][h][hp][c'][jj]
        const int h = jl >> 4, hp = (jl >> 3) & 1, jj = jl & 7;
        const int c0 = (g - 2) * 8;
        ushort* vt = ws + WSV + (size_t)b * 262144;
#pragma unroll
        for (int o = 0; o < 8; o++) {
            const int c = c0 + o, ct = c >> 5, cp = c & 31;
            vt[(size_t)((((jt * 2 + ct) * 2 + h) * 2 + hp) * 256) + cp * 8 + jj] = f2bf(acc[o]);
        }
    }
}

// ---------------- LDS-free MFMA flash attention ----------------
// grid (128, 4): 32-query tile, 256 thr = 4 waves; wave w owns keys j0 = t*128 + w*32.
__global__ __launch_bounds__(256, 2) void attn_kernel(
    const ushort* __restrict__ ws, const float* __restrict__ x,
    const float* __restrict__ gamma, float* __restrict__ out)
{
    __shared__ float Obuf[4][64][36];     // [wave][c][m], pitch 36 (16B-aligned, conflict-free)
    __shared__ float Lbuf[4][32];
    __shared__ float Linv[32];

    const int tid  = threadIdx.x;
    const int wid  = tid >> 6;
    const int lane = tid & 63;
    const int hl   = lane >> 5;
    const int col  = lane & 31;
    const int b    = blockIdx.y;
    const int qt   = blockIdx.x;

    const ushort* qf = ws + WSQ + (size_t)b * 65536 + (size_t)qt * 512;
    const ushort* kf = ws + WSK + (size_t)b * 65536;
    const ushort* vt = ws + WSV + (size_t)b * 262144;

    // Q B-frag (loop-invariant): B[k=d][n=m], lane-contiguous by construction
    const short8 qfrag = *(const short8*)(qf + lane * 8);

    f32x16 acc0, acc1, zf;
#pragma unroll
    for (int r = 0; r < 16; r++) { acc0[r] = 0.f; acc1[r] = 0.f; zf[r] = 0.f; }
    float lsum = 0.f;

    // register prefetch of tile t=0
    int jt = wid;
    uint4v kn   = *(const uint4v*)(kf + (size_t)jt * 512 + lane * 8);
    uint4v vn00 = *(const uint4v*)(vt + (size_t)((jt * 2 + 0) * 2 + 0) * 512 + lane * 8);
    uint4v vn01 = *(const uint4v*)(vt + (size_t)((jt * 2 + 0) * 2 + 1) * 512 + lane * 8);
    uint4v vn10 = *(const uint4v*)(vt + (size_t)((jt * 2 + 1) * 2 + 0) * 512 + lane * 8);
    uint4v vn11 = *(const uint4v*)(vt + (size_t)((jt * 2 + 1) * 2 + 1) * 512 + lane * 8);

    for (int t = 0; t < 32; t++) {
        const uint4v kc = kn, c00 = vn00, c01 = vn01, c10 = vn10, c11 = vn11;
        if (t < 31) {                        // prefetch t+1 under compute
            const int jn = jt + 4;
            kn   = *(const uint4v*)(kf + (size_t)jn * 512 + lane * 8);
            vn00 = *(const uint4v*)(vt + (size_t)((jn * 2 + 0) * 2 + 0) * 512 + lane * 8);
            vn01 = *(const uint4v*)(vt + (size_t)((jn * 2 + 0) * 2 + 1) * 512 + lane * 8);
            vn10 = *(const uint4v*)(vt + (size_t)((jn * 2 + 1) * 2 + 0) * 512 + lane * 8);
            vn11 = *(const uint4v*)(vt + (size_t)((jn * 2 + 1) * 2 + 1) * 512 + lane * 8);
        }

        // S^T[j][m] = K·Q^T  (one 32x32x16 MFMA; masking folded into d=8 slot)
        const f32x16 s = __builtin_amdgcn_mfma_f32_32x32x16_bf16(
            *(const short8*)&kc, qfrag, zf, 0, 0, 0);

        // p = exp2(s)  (log2e pre-folded into q); l accumulates per-lane
        float p[16];
#pragma unroll
        for (int r = 0; r < 16; r++) p[r] = __builtin_amdgcn_exp2f(s[r]);
#pragma unroll
        for (int r = 0; r < 16; r++) lsum += p[r];

        // pack to bf16 pairs (j-adjacent within reg pairs of C-layout)
        uint P[8];
#pragma unroll
        for (int r = 0; r < 8; r++) P[r] = pkbf(p[2 * r], p[2 * r + 1]);
        uint S[8];
#pragma unroll
        for (int r = 0; r < 8; r++) S[r] = (uint)__shfl_xor((int)P[r], 32);

        // P^T B-frags: C-layout rows vs B-frag k-halves differ only across lane>>5
        uint4v B0v, B1v;
        B0v.x = hl ? S[2] : P[0];  B0v.y = hl ? S[3] : P[1];
        B0v.z = hl ? P[2] : S[0];  B0v.w = hl ? P[3] : S[1];
        B1v.x = hl ? S[6] : P[4];  B1v.y = hl ? S[7] : P[5];
        B1v.z = hl ? P[6] : S[4];  B1v.w = hl ? P[7] : S[5];

        // O^T[c][m] += V^T·P^T   (A = vtf frags, B = P^T)
        acc0 = __builtin_amdgcn_mfma_f32_32x32x16_bf16(*(const short8*)&c00, *(const short8*)&B0v, acc0, 0, 0, 0);
        acc0 = __builtin_amdgcn_mfma_f32_32x32x16_bf16(*(const short8*)&c01, *(const short8*)&B1v, acc0, 0, 0, 0);
        acc1 = __builtin_amdgcn_mfma_f32_32x32x16_bf16(*(const short8*)&c10, *(const short8*)&B0v, acc1, 0, 0, 0);
        acc1 = __builtin_amdgcn_mfma_f32_32x32x16_bf16(*(const short8*)&c11, *(const short8*)&B1v, acc1, 0, 0, 0);

        jt += 4;
    }

    // ---- 4-way wave merge (waves held disjoint keys) ----
    const float lw = lsum + __shfl_xor(lsum, 32);     // both C-layout row-halves of l[m]
#pragma unroll
    for (int r = 0; r < 16; r++) {
        const int crow = (r & 3) + 8 * (r >> 2) + 4 * hl;   // verified 32x32 C/D mapping
        Obuf[wid][crow][col]      = acc0[r];
        Obuf[wid][32 + crow][col] = acc1[r];
    }
    if (hl == 0) Lbuf[wid][col] = lw;
    __syncthreads();
    if (tid < 32) Linv[tid] = 1.f / (Lbuf[0][tid] + Lbuf[1][tid] + Lbuf[2][tid] + Lbuf[3][tid]);
    __syncthreads();

    // ---- epilogue: out = gamma * O/l + x, coalesced fp32 ----
    const float gm = gamma[0];
    const int c = tid >> 2, ms = (tid & 3) * 8;
    f32x4 o0 = {0.f, 0.f, 0.f, 0.f}, o1 = {0.f, 0.f, 0.f, 0.f};
#pragma unroll
    for (int w = 0; w < 4; w++) {
        o0 += *(const f32x4*)&Obuf[w][c][ms];
        o1 += *(const f32x4*)&Obuf[w][c][ms + 4];
    }
    const size_t base = (((size_t)(b * CH + c)) << 12) + qt * 32 + ms;
    const f32x4 x0 = *(const f32x4*)&x[base];
    const f32x4 x1 = *(const f32x4*)&x[base + 4];
    f32x4 r0, r1;
#pragma unroll
    for (int u = 0; u < 4; u++) {
        r0[u] = gm * o0[u] * Linv[ms + u]     + x0[u];
        r1[u] = gm * o1[u] * Linv[ms + 4 + u] + x1[u];
    }
    *(f32x4*)&out[base]     = r0;
    *(f32x4*)&out[base + 4] = r1;
}

extern "C" void kernel_launch(void* const* d_in, const int* in_sizes, int n_in,
                              void* d_out, int out_size, void* d_ws, size_t ws_size,
                              hipStream_t stream) {
    const float* x     = (const float*)d_in[0];
    const int*   mask  = (const int*)d_in[1];
    const float* Wq    = (const float*)d_in[2];
    const float* bq    = (const float*)d_in[3];
    const float* Wk    = (const float*)d_in[4];
    const float* bk    = (const float*)d_in[5];
    const float* Wv    = (const float*)d_in[6];
    const float* bv    = (const float*)d_in[7];
    const float* gamma = (const float*)d_in[8];
    float* out  = (float*)d_out;
    ushort* ws  = (ushort*)d_ws;     // 1,572,864 u16 = 3.1 MB

    proj_kernel<<<dim3(64, 10), 256, 0, stream>>>(x, mask, Wq, bq, Wk, bk, Wv, bv, ws);
    attn_kernel<<<dim3(128, 4), 256, 0, stream>>>(ws, x, gamma, out);
}

// Round 8
// 101.582 us; speedup vs baseline: 4.6976x; 1.0024x over previous
//
#include <hip/hip_runtime.h>

typedef unsigned int uint;
typedef unsigned short ushort;
typedef __attribute__((ext_vector_type(8))) short short8;    // 8 bf16 MFMA A/B frag
typedef __attribute__((ext_vector_type(4))) float f32x4;
typedef __attribute__((ext_vector_type(16))) float f32x16;   // 32x32 MFMA C/D
typedef __attribute__((ext_vector_type(4))) uint uint4v;

#define BATCH 4
#define CH 64
#define NPIX 4096
#define LOG2E 1.44269504f

// ws layout (ushort elems), all bf16 in MFMA-frag-major order:
// qf[b][qt:128][h:2][m':32][jj:8]                       (d=16: 8 real + slot(qm?1:0) + zeros)
// kf[b][jt:128][h:2][j':32][jj:8]                       (d=16: 8 real + slot(km?0:-1e30) + zeros)
// vtf[b][jt:128][ct:2][h:2][hp:2][c':32][jj:8]
#define WSQ 0
#define WSK (BATCH * 128 * 512)          // 262144
#define WSV (2 * BATCH * 128 * 512)      // 524288 (vtf: 1048576 u16)

__device__ __forceinline__ ushort f2bf(float f) {            // RNE f32->bf16 (proj only)
    union { float f; uint u; } a; a.f = f;
    const uint u = a.u;
    return (ushort)((u + 0x7FFFu + ((u >> 16) & 1u)) >> 16);
}
__device__ __forceinline__ uint pkbf(float a, float b) {     // RNE pack (proj only)
    return (uint)f2bf(a) | ((uint)f2bf(b) << 16);
}
// fast round-half-up pack for P in the attn hot loop: 3 VALU ops vs ~9.
// bias vs RNE <= 2^-17 relative; p>=0 finite, no NaN path.
__device__ __forceinline__ uint pkbf_fu(float a, float b) {
    union { float f; uint u; } x, y; x.f = a; y.f = b;
    return ((y.u + 0x8000u) & 0xFFFF0000u) | ((x.u + 0x8000u) >> 16);
}

// ---------------- projections -> frag-major bf16 q,k,v ----------------
// grid (64, 9): x = 256-pixel tile, y = group (0 = q+k fused, 1..8 = v rows 8(g-1))
__global__ __launch_bounds__(256) void proj_kernel(
    const float* __restrict__ x, const int* __restrict__ mask,
    const float* __restrict__ Wq, const float* __restrict__ bq,
    const float* __restrict__ Wk, const float* __restrict__ bk,
    const float* __restrict__ Wv, const float* __restrict__ bv,
    ushort* __restrict__ ws)
{
    __shared__ float wsh[16 * 64];
    __shared__ float bsh[16];
    const int g = blockIdx.y;
    const int tid = threadIdx.x;
    const int nout = (g == 0) ? 16 : 8;

    if (g == 0) {
        for (int i = tid; i < 512; i += 256) { wsh[i] = Wq[i]; wsh[512 + i] = Wk[i]; }
        if (tid < 8)  bsh[tid] = bq[tid];
        else if (tid < 16) bsh[tid] = bk[tid - 8];
    } else {
        const float* W = Wv + (g - 1) * 512;
        for (int i = tid; i < 512; i += 256) wsh[i] = W[i];
        if (tid < 8) bsh[tid] = bv[(g - 1) * 8 + tid];
    }
    __syncthreads();

    const int pix = blockIdx.x * 256 + tid;          // 0..16383
    const int b = pix >> 12;
    const int n = pix & (NPIX - 1);
    const float* xb = x + (size_t)b * CH * NPIX + n;

    float acc[16];
#pragma unroll
    for (int o = 0; o < 16; o++) acc[o] = (o < nout) ? bsh[o] : 0.f;

#pragma unroll
    for (int c4 = 0; c4 < 16; c4++) {
        float xv0 = xb[(size_t)(c4 * 4 + 0) * NPIX];
        float xv1 = xb[(size_t)(c4 * 4 + 1) * NPIX];
        float xv2 = xb[(size_t)(c4 * 4 + 2) * NPIX];
        float xv3 = xb[(size_t)(c4 * 4 + 3) * NPIX];
        if (g == 0) {
#pragma unroll
            for (int o = 0; o < 16; o++) {
                const int base = (o < 8 ? 0 : 512) + (o & 7) * 64;
                float4 w = *(const float4*)&wsh[base + c4 * 4];
                acc[o] += w.x * xv0 + w.y * xv1 + w.z * xv2 + w.w * xv3;
            }
        } else {
#pragma unroll
            for (int o = 0; o < 8; o++) {
                float4 w = *(const float4*)&wsh[o * 64 + c4 * 4];
                acc[o] += w.x * xv0 + w.y * xv1 + w.z * xv2 + w.w * xv3;
            }
        }
    }

    const int jt = n >> 5, jl = n & 31;
    if (g == 0) {
        const int qm = mask[pix];
        // q: fold log2(e); zero rows of invalid queries; d=8 slot = qm?1:0
        {
            const float s = qm ? LOG2E : 0.f;
            uint4v lo, hi;
            lo.x = pkbf(acc[0] * s, acc[1] * s);
            lo.y = pkbf(acc[2] * s, acc[3] * s);
            lo.z = pkbf(acc[4] * s, acc[5] * s);
            lo.w = pkbf(acc[6] * s, acc[7] * s);
            hi.x = qm ? 0x3F80u : 0u;   // bf16(1.0) in slot jj=0
            hi.y = 0u; hi.z = 0u; hi.w = 0u;
            ushort* qf = ws + WSQ + (size_t)b * 65536 + (size_t)jt * 512;
            *(uint4v*)(qf + jl * 8)       = lo;   // h=0: real d 0..7
            *(uint4v*)(qf + 256 + jl * 8) = hi;   // h=1: d 8..15
        }
        // k: d=8 slot = km ? 0 : -1e30  (masked keys annihilate via exp2)
        {
            uint4v lo, hi;
            lo.x = pkbf(acc[8],  acc[9]);
            lo.y = pkbf(acc[10], acc[11]);
            lo.z = pkbf(acc[12], acc[13]);
            lo.w = pkbf(acc[14], acc[15]);
            hi.x = (uint)f2bf(qm ? 0.f : -1e30f);
            hi.y = 0u; hi.z = 0u; hi.w = 0u;
            ushort* kf = ws + WSK + (size_t)b * 65536 + (size_t)jt * 512;
            *(uint4v*)(kf + jl * 8)       = lo;
            *(uint4v*)(kf + 256 + jl * 8) = hi;
        }
    } else {
        // v: frag-major vtf[b][jt][ct][h][hp][c'][jj]
        const int h = jl >> 4, hp = (jl >> 3) & 1, jj = jl & 7;
        const int c0 = (g - 1) * 8;
        ushort* vt = ws + WSV + (size_t)b * 262144;
#pragma unroll
        for (int o = 0; o < 8; o++) {
            const int c = c0 + o, ct = c >> 5, cp = c & 31;
            vt[(size_t)((((jt * 2 + ct) * 2 + h) * 2 + hp) * 256) + cp * 8 + jj] = f2bf(acc[o]);
        }
    }
}

// ---------------- LDS-free MFMA flash attention ----------------
// grid (128, 4): 32-query tile, 256 thr = 4 waves; wave w owns keys j0 = t*128 + w*32.
__global__ __launch_bounds__(256, 2) void attn_kernel(
    const ushort* __restrict__ ws, const float* __restrict__ x,
    const float* __restrict__ gamma, float* __restrict__ out)
{
    __shared__ float Obuf[4][64][36];     // [wave][c][m], pitch 36 (16B-aligned, conflict-free)
    __shared__ float Lbuf[4][32];
    __shared__ float Linv[32];

    const int tid  = threadIdx.x;
    const int wid  = tid >> 6;
    const int lane = tid & 63;
    const int hl   = lane >> 5;
    const int col  = lane & 31;
    const int b    = blockIdx.y;
    const int qt   = blockIdx.x;

    const ushort* qf = ws + WSQ + (size_t)b * 65536 + (size_t)qt * 512;
    const ushort* kf = ws + WSK + (size_t)b * 65536;
    const ushort* vt = ws + WSV + (size_t)b * 262144;

    // Q B-frag (loop-invariant): B[k=d][n=m], lane-contiguous by construction
    const short8 qfrag = *(const short8*)(qf + lane * 8);

    f32x16 acc0, acc1, zf;
#pragma unroll
    for (int r = 0; r < 16; r++) { acc0[r] = 0.f; acc1[r] = 0.f; zf[r] = 0.f; }
    float lsum = 0.f;

    // register prefetch of tile t=0
    int jt = wid;
    uint4v kn   = *(const uint4v*)(kf + (size_t)jt * 512 + lane * 8);
    uint4v vn00 = *(const uint4v*)(vt + (size_t)((jt * 2 + 0) * 2 + 0) * 512 + lane * 8);
    uint4v vn01 = *(const uint4v*)(vt + (size_t)((jt * 2 + 0) * 2 + 1) * 512 + lane * 8);
    uint4v vn10 = *(const uint4v*)(vt + (size_t)((jt * 2 + 1) * 2 + 0) * 512 + lane * 8);
    uint4v vn11 = *(const uint4v*)(vt + (size_t)((jt * 2 + 1) * 2 + 1) * 512 + lane * 8);

    for (int t = 0; t < 32; t++) {
        const uint4v kc = kn, c00 = vn00, c01 = vn01, c10 = vn10, c11 = vn11;
        if (t < 31) {                        // prefetch t+1 under compute
            const int jn = jt + 4;
            kn   = *(const uint4v*)(kf + (size_t)jn * 512 + lane * 8);
            vn00 = *(const uint4v*)(vt + (size_t)((jn * 2 + 0) * 2 + 0) * 512 + lane * 8);
            vn01 = *(const uint4v*)(vt + (size_t)((jn * 2 + 0) * 2 + 1) * 512 + lane * 8);
            vn10 = *(const uint4v*)(vt + (size_t)((jn * 2 + 1) * 2 + 0) * 512 + lane * 8);
            vn11 = *(const uint4v*)(vt + (size_t)((jn * 2 + 1) * 2 + 1) * 512 + lane * 8);
        }

        // S^T[j][m] = K·Q^T  (one 32x32x16 MFMA; masking folded into d=8 slot)
        const f32x16 s = __builtin_amdgcn_mfma_f32_32x32x16_bf16(
            *(const short8*)&kc, qfrag, zf, 0, 0, 0);

        // p = exp2(s)  (log2e pre-folded into q); l accumulates per-lane
        float p[16];
#pragma unroll
        for (int r = 0; r < 16; r++) p[r] = __builtin_amdgcn_exp2f(s[r]);
#pragma unroll
        for (int r = 0; r < 16; r++) lsum += p[r];

        // pack to bf16 pairs (j-adjacent within reg pairs of C-layout), half-up
        uint P[8];
#pragma unroll
        for (int r = 0; r < 8; r++) P[r] = pkbf_fu(p[2 * r], p[2 * r + 1]);
        uint S[8];
#pragma unroll
        for (int r = 0; r < 8; r++) S[r] = (uint)__shfl_xor((int)P[r], 32);

        // P^T B-frags: C-layout rows vs B-frag k-halves differ only across lane>>5
        uint4v B0v, B1v;
        B0v.x = hl ? S[2] : P[0];  B0v.y = hl ? S[3] : P[1];
        B0v.z = hl ? P[2] : S[0];  B0v.w = hl ? P[3] : S[1];
        B1v.x = hl ? S[6] : P[4];  B1v.y = hl ? S[7] : P[5];
        B1v.z = hl ? P[6] : S[4];  B1v.w = hl ? P[7] : S[5];

        // O^T[c][m] += V^T·P^T   (A = vtf frags, B = P^T)
        acc0 = __builtin_amdgcn_mfma_f32_32x32x16_bf16(*(const short8*)&c00, *(const short8*)&B0v, acc0, 0, 0, 0);
        acc0 = __builtin_amdgcn_mfma_f32_32x32x16_bf16(*(const short8*)&c01, *(const short8*)&B1v, acc0, 0, 0, 0);
        acc1 = __builtin_amdgcn_mfma_f32_32x32x16_bf16(*(const short8*)&c10, *(const short8*)&B0v, acc1, 0, 0, 0);
        acc1 = __builtin_amdgcn_mfma_f32_32x32x16_bf16(*(const short8*)&c11, *(const short8*)&B1v, acc1, 0, 0, 0);

        jt += 4;
    }

    // ---- 4-way wave merge (waves held disjoint keys) ----
    const float lw = lsum + __shfl_xor(lsum, 32);     // both C-layout row-halves of l[m]
#pragma unroll
    for (int r = 0; r < 16; r++) {
        const int crow = (r & 3) + 8 * (r >> 2) + 4 * hl;   // verified 32x32 C/D mapping
        Obuf[wid][crow][col]      = acc0[r];
        Obuf[wid][32 + crow][col] = acc1[r];
    }
    if (hl == 0) Lbuf[wid][col] = lw;
    __syncthreads();
    if (tid < 32) Linv[tid] = 1.f / (Lbuf[0][tid] + Lbuf[1][tid] + Lbuf[2][tid] + Lbuf[3][tid]);
    __syncthreads();

    // ---- epilogue: out = gamma * O/l + x, coalesced fp32 ----
    const float gm = gamma[0];
    const int c = tid >> 2, ms = (tid & 3) * 8;
    f32x4 o0 = {0.f, 0.f, 0.f, 0.f}, o1 = {0.f, 0.f, 0.f, 0.f};
#pragma unroll
    for (int w = 0; w < 4; w++) {
        o0 += *(const f32x4*)&Obuf[w][c][ms];
        o1 += *(const f32x4*)&Obuf[w][c][ms + 4];
    }
    const size_t base = (((size_t)(b * CH + c)) << 12) + qt * 32 + ms;
    const f32x4 x0 = *(const f32x4*)&x[base];
    const f32x4 x1 = *(const f32x4*)&x[base + 4];
    f32x4 r0, r1;
#pragma unroll
    for (int u = 0; u < 4; u++) {
        r0[u] = gm * o0[u] * Linv[ms + u]     + x0[u];
        r1[u] = gm * o1[u] * Linv[ms + 4 + u] + x1[u];
    }
    *(f32x4*)&out[base]     = r0;
    *(f32x4*)&out[base + 4] = r1;
}

extern "C" void kernel_launch(void* const* d_in, const int* in_sizes, int n_in,
                              void* d_out, int out_size, void* d_ws, size_t ws_size,
                              hipStream_t stream) {
    const float* x     = (const float*)d_in[0];
    const int*   mask  = (const int*)d_in[1];
    const float* Wq    = (const float*)d_in[2];
    const float* bq    = (const float*)d_in[3];
    const float* Wk    = (const float*)d_in[4];
    const float* bk    = (const float*)d_in[5];
    const float* Wv    = (const float*)d_in[6];
    const float* bv    = (const float*)d_in[7];
    const float* gamma = (const float*)d_in[8];
    float* out  = (float*)d_out;
    ushort* ws  = (ushort*)d_ws;     // 1,572,864 u16 = 3.1 MB

    proj_kernel<<<dim3(64, 9), 256, 0, stream>>>(x, mask, Wq, bq, Wk, bk, Wv, bv, ws);
    attn_kernel<<<dim3(128, 4), 256, 0, stream>>>(ws, x, gamma, out);
}